// Round 1
// 440.438 us; speedup vs baseline: 1.0539x; 1.0539x over previous
//
#include <hip/hip_runtime.h>

#define EPS 1e-6f

typedef __attribute__((ext_vector_type(8))) __bf16 bf16x8;
typedef __attribute__((ext_vector_type(4))) float f32x4;
typedef __attribute__((ext_vector_type(4))) unsigned short us4v;
typedef __attribute__((ext_vector_type(8))) unsigned short us8v;
typedef unsigned short us;

__device__ inline us f2bf(float f) {
  unsigned int u = __builtin_bit_cast(unsigned int, f);
  unsigned int r = (u + 0x7fffu + ((u >> 16) & 1u)) >> 16;
  return (us)r;
}
__device__ inline float bf2f(us s) {
  unsigned int u = ((unsigned int)s) << 16;
  return __builtin_bit_cast(float, u);
}

__device__ inline void gl_lds16(const us* g, us* l) {
  __builtin_amdgcn_global_load_lds(
      (const __attribute__((address_space(1))) unsigned int*)g,
      (__attribute__((address_space(3))) unsigned int*)l, 16, 0, 0);
}

// ---------------------------------------------------------------------------
// fp32 -> bf16 convert (RNE), n elements (multiple of 2048). grid = n/2048.
// ---------------------------------------------------------------------------
__global__ __launch_bounds__(256) void conv_bf16(const float* __restrict__ s,
                                                 us* __restrict__ d) {
  int idx = blockIdx.x * 256 + threadIdx.x;
  size_t base = (size_t)idx * 8;
  float4 a = *(const float4*)(s + base);
  float4 b = *(const float4*)(s + base + 4);
  us8v o;
  o[0] = f2bf(a.x); o[1] = f2bf(a.y); o[2] = f2bf(a.z); o[3] = f2bf(a.w);
  o[4] = f2bf(b.x); o[5] = f2bf(b.y); o[6] = f2bf(b.z); o[7] = f2bf(b.w);
  *(us8v*)(d + base) = o;
}

// ---------------------------------------------------------------------------
// Projection GEMM, all-bf16, deep-pipelined counted-vmcnt schedule:
//   256x256 tile, BK=32, 4-deep LDS ring (128 KiB), 512 threads / 8 waves,
//   raw s_barrier + s_waitcnt vmcnt(12) (prefetch distance 3 K-tiles,
//   never drained to 0 in the main loop), setprio around the MFMA cluster.
// Y[i][j] = act( sum_k X[i][k] * W[j][k] + bias[j] )
// MODE 0: phi (elu+1), store bf16 row-major           (q projection)
// MODE 1: phi,         store bf16 transposed per head (k -> kt[bh][d][m])
// MODE 2: identity,    store bf16 transposed per head (v -> vt[bh][e][m])
// MODE 3: identity,    store fp32 row-major           (output projection)
// grid: 256 blocks, 1 block/CU. XCD-bijective swizzle: xcd = bid&7 owns
// 8 contiguous row-groups x all 4 col-groups -> W (2MB) L2-resident/XCD,
// X fetched from HBM once.
//
// Ring-buffer race ledger (safe by construction):
//   step t: stage tile t+3 -> buf[(t+3)&3] == buf[(t-1)&3]; its reads all
//   completed before the trailing barrier of step t-1, which precedes this
//   issue. vmcnt(12) + barrier at step t guarantees tile t's loads (>=12
//   issues old, all waves) have landed before any ds_read of buf[t&3].
//   Tail drain: vmcnt 12 -> 8 (t=29) -> 4 (t=30) -> 0 (t=31).
// ---------------------------------------------------------------------------
template <int MODE>
__global__ __launch_bounds__(512, 2) void proj_gemm(const us* __restrict__ X,
                                                    const us* __restrict__ W,
                                                    const float* __restrict__ bias,
                                                    void* __restrict__ Yv) {
  __shared__ alignas(16) us As[4][256 * 32];   // 4 ring slots, 16 KB each
  __shared__ alignas(16) us Bs[4][256 * 32];

  const int t = threadIdx.x;
  const int wave = t >> 6, lane = t & 63;
  const int q4 = lane >> 4, l16 = lane & 15;
  const int wm = wave >> 2, wn = wave & 3;     // 2 (M) x 4 (N) wave grid
  const int bid = blockIdx.x;
  // bijective XCD swizzle: xcd = bid&7, rowg = xcd*8 + (bid>>5), colg = (bid>>3)&3
  const int rowg = (bid & 7) * 8 + (bid >> 5);  // 0..63
  const int colg = (bid >> 3) & 3;              // 0..3
  const int rowBase = rowg << 8;
  const int colBase = colg << 8;

  // staging: per K-tile per operand = 256 rows x 32 k = 16 KB = 2 issues of
  // 512 lanes x 16 B. chunk = i*512 + t; row = i*128 + (t>>2); pos = t&3.
  // source k-chunk pre-swizzled: spos = pos ^ ((row>>1)&3) = (t&3)^((t>>3)&3).
  const int spos = (t & 3) ^ ((t >> 3) & 3);
  const us* Xg = X + (size_t)(rowBase + (t >> 2)) * 1024 + spos * 8;
  const us* Wg = W + (size_t)(colBase + (t >> 2)) * 1024 + spos * 8;
  // read-side swizzled k-chunk (us offset), constant per lane:
  const int cA = (q4 ^ ((l16 >> 1) & 3)) * 8;

  f32x4 acc[8][4];
#pragma unroll
  for (int i = 0; i < 8; i++)
#pragma unroll
    for (int j = 0; j < 4; j++) acc[i][j] = (f32x4){0.f, 0.f, 0.f, 0.f};

#define STAGEP(tt)                                                         \
  {                                                                        \
    const int k0_ = (tt) * 32;                                             \
    us* Ad_ = &As[(tt) & 3][wave * 64 * 8];                                \
    us* Bd_ = &Bs[(tt) & 3][wave * 64 * 8];                                \
    gl_lds16(Xg + k0_, Ad_);                                               \
    gl_lds16(Xg + (size_t)128 * 1024 + k0_, Ad_ + 512 * 8);                \
    gl_lds16(Wg + k0_, Bd_);                                               \
    gl_lds16(Wg + (size_t)128 * 1024 + k0_, Bd_ + 512 * 8);                \
  }

  // prologue: 3 tiles in flight
  STAGEP(0);
  STAGEP(1);
  STAGEP(2);

#pragma unroll 4
  for (int tt = 0; tt < 32; ++tt) {
    if (tt < 29) {
      STAGEP(tt + 3);
      asm volatile("s_waitcnt vmcnt(12)" ::: "memory");  // tile tt landed
    } else if (tt == 29) {
      asm volatile("s_waitcnt vmcnt(8)" ::: "memory");
    } else if (tt == 30) {
      asm volatile("s_waitcnt vmcnt(4)" ::: "memory");
    } else {
      asm volatile("s_waitcnt vmcnt(0)" ::: "memory");
    }
    asm volatile("s_barrier" ::: "memory");  // publish tile tt (no drain)

    const us* Ab = &As[tt & 3][0];
    const us* Bb2 = &Bs[tt & 3][0];
    bf16x8 af[8], bfv[4];
#pragma unroll
    for (int i = 0; i < 8; i++)
      af[i] = *(const bf16x8*)&Ab[(wm * 128 + i * 16 + l16) * 32 + cA];
#pragma unroll
    for (int j = 0; j < 4; j++)
      bfv[j] = *(const bf16x8*)&Bb2[(wn * 64 + j * 16 + l16) * 32 + cA];

    __builtin_amdgcn_s_setprio(1);
#pragma unroll
    for (int i = 0; i < 8; i++)
#pragma unroll
      for (int j = 0; j < 4; j++)
        acc[i][j] = __builtin_amdgcn_mfma_f32_16x16x32_bf16(af[i], bfv[j],
                                                            acc[i][j], 0, 0, 0);
    __builtin_amdgcn_s_setprio(0);

    asm volatile("s_barrier" ::: "memory");  // release buf[tt&3] for restage
  }
#undef STAGEP

  // epilogue
#pragma unroll
  for (int j = 0; j < 4; j++) {
    int col = colBase + wn * 64 + j * 16 + l16;
    float bv = bias[col];
#pragma unroll
    for (int i = 0; i < 8; i++) {
      int row0 = rowBase + wm * 128 + i * 16 + q4 * 4;
      if (MODE == 1 || MODE == 2) {
        int b = row0 >> 12, m0 = row0 & 4095;
        int h = col >> 6, dd = col & 63;
        us4v pk;
#pragma unroll
        for (int r = 0; r < 4; r++) {
          float y = acc[i][j][r] + bv;
          if (MODE == 1) y = (y > 0.f) ? (y + 1.f) : __expf(y);
          pk[r] = f2bf(y);
        }
        *(us4v*)&((us*)Yv)[(((size_t)((b * 16 + h) * 64 + dd)) << 12) + m0] = pk;
      } else {
#pragma unroll
        for (int r = 0; r < 4; r++) {
          float y = acc[i][j][r] + bv;
          if (MODE == 0) {
            y = (y > 0.f) ? (y + 1.f) : __expf(y);
            ((us*)Yv)[(size_t)(row0 + r) * 1024 + col] = f2bf(y);
          } else {
            ((float*)Yv)[(size_t)(row0 + r) * 1024 + col] = y;
          }
        }
      }
    }
  }
}

// ---------------------------------------------------------------------------
// kv stage 1: partial kv_t[e][d] = sum_m vt[e][m]*kt[d][m] over a 1024-m slab,
// plus z-partials folded from the kt B-fragments. 256 blocks (bh x 4 splits),
// 4 waves each covering 256 m. LDS tree-reduce, plain stores (no atomics).
// ---------------------------------------------------------------------------
__global__ __launch_bounds__(256) void kv_stage1(const us* __restrict__ kt,
                                                 const us* __restrict__ vt,
                                                 float* __restrict__ part,
                                                 float* __restrict__ zpart) {
  __shared__ float red[4][4096];
  __shared__ float zred[4][64][4];

  const int blk = blockIdx.x;
  const int bh = blk >> 2, split = blk & 3;
  const int t = threadIdx.x;
  const int w = t >> 6, lane = t & 63;
  const int q4 = lane >> 4, l16 = lane & 15;
  const us* ktb = kt + (size_t)bh * 64 * 4096;
  const us* vtb = vt + (size_t)bh * 64 * 4096;
  const int mbeg = split * 1024 + w * 256;

  f32x4 acc[4][4];
#pragma unroll
  for (int i = 0; i < 4; i++)
#pragma unroll
    for (int j = 0; j < 4; j++) acc[i][j] = (f32x4){0.f, 0.f, 0.f, 0.f};
  float zacc[4] = {0.f, 0.f, 0.f, 0.f};

  for (int m0 = mbeg; m0 < mbeg + 256; m0 += 32) {
    bf16x8 af[4], bfr[4];
#pragma unroll
    for (int i = 0; i < 4; i++)
      af[i] = *(const bf16x8*)&vtb[(size_t)(i * 16 + l16) * 4096 + m0 + q4 * 8];
#pragma unroll
    for (int j = 0; j < 4; j++) {
      us8v ub = *(const us8v*)&ktb[(size_t)(j * 16 + l16) * 4096 + m0 + q4 * 8];
      bfr[j] = __builtin_bit_cast(bf16x8, ub);
#pragma unroll
      for (int e = 0; e < 8; e++) zacc[j] += bf2f(ub[e]);
    }
#pragma unroll
    for (int i = 0; i < 4; i++)
#pragma unroll
      for (int j = 0; j < 4; j++)
        acc[i][j] = __builtin_amdgcn_mfma_f32_16x16x32_bf16(af[i], bfr[j], acc[i][j], 0, 0, 0);
  }

#pragma unroll
  for (int i = 0; i < 4; i++)
#pragma unroll
    for (int j = 0; j < 4; j++)
#pragma unroll
      for (int r = 0; r < 4; r++)
        red[w][(i * 16 + q4 * 4 + r) * 64 + j * 16 + l16] = acc[i][j][r];
#pragma unroll
  for (int j = 0; j < 4; j++) zred[w][j * 16 + l16][q4] = zacc[j];
  __syncthreads();

  float* pb = part + (size_t)blk * 4096;
#pragma unroll
  for (int i = 0; i < 16; i++) {
    int idx = t + 256 * i;
    pb[idx] = red[0][idx] + red[1][idx] + red[2][idx] + red[3][idx];
  }
  if (t < 64) {
    float s = 0.f;
#pragma unroll
    for (int w2 = 0; w2 < 4; w2++)
#pragma unroll
      for (int q = 0; q < 4; q++) s += zred[w2][t][q];
    zpart[blk * 64 + t] = s;
  }
}

// stage 2: reduce the 4 split-partials -> kv bf16 + z fp32. 64 blocks.
__global__ __launch_bounds__(256) void kv_stage2(const float* __restrict__ part,
                                                 const float* __restrict__ zpart,
                                                 us* __restrict__ kvb,
                                                 float* __restrict__ z) {
  const int bh = blockIdx.x;
  const int t = threadIdx.x;
  const float* p0 = part + (size_t)bh * 4 * 4096;
#pragma unroll
  for (int i = 0; i < 16; i++) {
    int idx = t + 256 * i;
    float s = p0[idx] + p0[4096 + idx] + p0[8192 + idx] + p0[12288 + idx];
    kvb[(size_t)bh * 4096 + idx] = f2bf(s);
  }
  if (t < 64) {
    const float* zp = zpart + (size_t)bh * 4 * 64;
    z[bh * 64 + t] = zp[t] + zp[64 + t] + zp[128 + t] + zp[192 + t];
  }
}

// ---------------------------------------------------------------------------
// attn[b][n][h*64+e] = (sum_d q[n][d] kv[d][e]) / (q[n]·z + eps), bf16,
// written IN PLACE over q (each block reads exactly the region it writes).
// ---------------------------------------------------------------------------
__global__ __launch_bounds__(256) void attn_kernel(const us* __restrict__ q,
                                                   const us* __restrict__ kvb,
                                                   const float* __restrict__ z,
                                                   us* __restrict__ attn) {
  __shared__ alignas(16) us kvs[64 * 72];
  __shared__ float zs[64];
  __shared__ float invden[256];

  const int bid = blockIdx.x;
  const int bh = bid >> 4, nc = bid & 15;
  const int b = bh >> 4, h = bh & 15;
  const int n0 = nc * 256;
  const int t = threadIdx.x;
  const int wave = t >> 6, lane = t & 63;
  const int q4 = lane >> 4, l16 = lane & 15;

#pragma unroll
  for (int i = 0; i < 2; i++) {
    int chunk = t + 256 * i;          // 0..511
    int e = chunk >> 3, d8 = chunk & 7;
    us8v vv = *(const us8v*)&kvb[(size_t)bh * 4096 + chunk * 8];
    *(us8v*)&kvs[e * 72 + d8 * 8] = vv;
  }
  if (t < 64) zs[t] = z[bh * 64 + t];
  __syncthreads();

  {
    const us* qrow = q + ((size_t)(b * 4096 + n0 + t)) * 1024 + h * 64;
    float s = 0.f;
#pragma unroll
    for (int d0 = 0; d0 < 64; d0 += 8) {
      us8v v = *(const us8v*)(qrow + d0);
#pragma unroll
      for (int j = 0; j < 8; j++) s += bf2f(v[j]) * zs[d0 + j];
    }
    invden[t] = 1.0f / (s + EPS);
  }
  __syncthreads();

  f32x4 acc[4][4];
#pragma unroll
  for (int i = 0; i < 4; i++)
#pragma unroll
    for (int j = 0; j < 4; j++) acc[i][j] = (f32x4){0.f, 0.f, 0.f, 0.f};

  const us* qb = q + ((size_t)(b * 4096 + n0 + wave * 64)) * 1024 + h * 64;
#pragma unroll
  for (int ks = 0; ks < 2; ks++) {
    bf16x8 af[4], bfr[4];
#pragma unroll
    for (int i = 0; i < 4; i++)
      af[i] = *(const bf16x8*)(qb + (size_t)(i * 16 + l16) * 1024 + ks * 32 + q4 * 8);
#pragma unroll
    for (int j = 0; j < 4; j++)
      bfr[j] = *(const bf16x8*)&kvs[(j * 16 + l16) * 72 + ks * 32 + q4 * 8];
#pragma unroll
    for (int i = 0; i < 4; i++)
#pragma unroll
      for (int j = 0; j < 4; j++)
        acc[i][j] = __builtin_amdgcn_mfma_f32_16x16x32_bf16(af[i], bfr[j], acc[i][j], 0, 0, 0);
  }

  us* ab = attn + ((size_t)(b * 4096 + n0 + wave * 64)) * 1024 + h * 64;
#pragma unroll
  for (int i = 0; i < 4; i++)
#pragma unroll
    for (int j = 0; j < 4; j++)
#pragma unroll
      for (int r = 0; r < 4; r++) {
        int rowl = i * 16 + q4 * 4 + r;
        int nl = wave * 64 + rowl;
        int e = j * 16 + l16;
        ab[(size_t)rowl * 1024 + e] = f2bf(acc[i][j][r] * invden[nl]);
      }
}

// ---------------------------------------------------------------------------
extern "C" void kernel_launch(void* const* d_in, const int* in_sizes, int n_in,
                              void* d_out, int out_size, void* d_ws, size_t ws_size,
                              hipStream_t stream) {
  const float* queries = (const float*)d_in[0];
  const float* keys    = (const float*)d_in[1];
  const float* values  = (const float*)d_in[2];
  const float* wq = (const float*)d_in[3];
  const float* bq = (const float*)d_in[4];
  const float* wk = (const float*)d_in[5];
  const float* bk = (const float*)d_in[6];
  const float* wv = (const float*)d_in[7];
  const float* bv = (const float*)d_in[8];
  const float* wo = (const float*)d_in[9];
  const float* bo = (const float*)d_in[10];

  char* ws = (char*)d_ws;
  const size_t TB = (size_t)16384 * 1024 * 2;   // 33.55 MB per big bf16 buffer
  us* A   = (us*)(ws);            // kt, later q/attn
  us* Bb  = (us*)(ws + TB);       // vt, later queries-bf16
  us* Xb  = (us*)(ws + 2 * TB);   // keys/values bf16 scratch
  us* wqb = (us*)(ws + 3 * TB);
  us* wkb = wqb + (size_t)1024 * 1024;
  us* wvb = wkb + (size_t)1024 * 1024;
  us* wob = wvb + (size_t)1024 * 1024;
  float* part  = (float*)(wob + (size_t)1024 * 1024);     // 256*4096 fp32
  float* zpart = part + (size_t)256 * 4096;               // 256*64
  float* z     = zpart + 256 * 64;                        // 4096
  us* kvb      = (us*)(z + 4096);                         // 64*4096 bf16

  const int GRID_IN = 16384 * 1024 / 2048;   // 8192
  const int GRID_W  = 1024 * 1024 / 2048;    // 512

  // weights -> bf16
  conv_bf16<<<GRID_W, 256, 0, stream>>>(wq, wqb);
  conv_bf16<<<GRID_W, 256, 0, stream>>>(wk, wkb);
  conv_bf16<<<GRID_W, 256, 0, stream>>>(wv, wvb);
  conv_bf16<<<GRID_W, 256, 0, stream>>>(wo, wob);

  // K projection
  conv_bf16<<<GRID_IN, 256, 0, stream>>>(keys, Xb);
  proj_gemm<1><<<256, 512, 0, stream>>>(Xb, wkb, bk, (void*)A);
  // V projection
  conv_bf16<<<GRID_IN, 256, 0, stream>>>(values, Xb);
  proj_gemm<2><<<256, 512, 0, stream>>>(Xb, wvb, bv, (void*)Bb);
  // kv + z
  kv_stage1<<<256, 256, 0, stream>>>(A, Bb, part, zpart);
  kv_stage2<<<64, 256, 0, stream>>>(part, zpart, kvb, z);
  // Q projection (kt/vt dead; reuse buffers)
  conv_bf16<<<GRID_IN, 256, 0, stream>>>(queries, Bb);
  proj_gemm<0><<<256, 512, 0, stream>>>(Bb, wqb, bq, (void*)A);
  // attention (in place over q)
  attn_kernel<<<1024, 256, 0, stream>>>(A, kvb, z, A);
  // output projection
  proj_gemm<3><<<256, 512, 0, stream>>>(A, wob, bo, d_out);
}